// Round 5
// baseline (1871.302 us; speedup 1.0000x reference)
//
#include <hip/hip_runtime.h>
#include <math.h>

// Problem constants (fixed by reference)
#define BATCH 2048
#define CH    32      // C
#define NN    144     // H*W = 12*12
#define KNN   9
#define PAD   36      // LDS row stride (floats): rows 2-way bank aliased = free
#define TPB   576     // 4 threads per node, one batch per block, 9 waves

// exact GELU: x * 0.5 * (1 + erf(x/sqrt(2)))  (jax.nn.gelu approximate=False)
__device__ __forceinline__ float gelu_exact(float x) {
    return 0.5f * x * (1.0f + erff(x * 0.70710678118654752440f));
}

// pick arr[8*s + oo] without dynamic register indexing (oo compile-time)
#define PICK8(arr, s, oo) ((s)==0 ? (arr)[oo] : (s)==1 ? (arr)[8+(oo)] : \
                           (s)==2 ? (arr)[16+(oo)] : (arr)[24+(oo)])

// ordered allgather of 8-chunks across a quad: out[32] = concat(chunk0..3)
__device__ __forceinline__ void quad_allgather(const float a[8], float out[32], int s) {
    float b[8];
    #pragma unroll
    for (int k = 0; k < 8; ++k) b[k] = __shfl_xor(a[k], 1);
    float p[16];
    const bool o1 = (s & 1);
    #pragma unroll
    for (int k = 0; k < 8; ++k) { p[k] = o1 ? b[k] : a[k]; p[8 + k] = o1 ? a[k] : b[k]; }
    float q[16];
    #pragma unroll
    for (int k = 0; k < 16; ++k) q[k] = __shfl_xor(p[k], 2);
    const bool o2 = (s & 2);
    #pragma unroll
    for (int k = 0; k < 16; ++k) { out[k] = o2 ? q[k] : p[k]; out[16 + k] = o2 ? p[k] : q[k]; }
}

// merge partner's sorted top-9 into mine; lex (d, idx) preserves lax.top_k tie-break
__device__ __forceinline__ void quad_merge(float bd[KNN], int bi[KNN], int mask) {
    float od[KNN]; int oi[KNN];
    #pragma unroll
    for (int k = 0; k < KNN; ++k) { od[k] = __shfl_xor(bd[k], mask); oi[k] = __shfl_xor(bi[k], mask); }
    #pragma unroll
    for (int k = 0; k < KNN; ++k) {
        float d = od[k]; int ix = oi[k];
        if (d < bd[KNN-1] || (d == bd[KNN-1] && ix < bi[KNN-1])) {
            bd[KNN-1] = d; bi[KNN-1] = ix;
            #pragma unroll
            for (int kk = KNN-1; kk > 0; --kk) {
                bool sw = bd[kk] < bd[kk-1] || (bd[kk] == bd[kk-1] && bi[kk] < bi[kk-1]);
                if (sw) {
                    float td = bd[kk]; bd[kk] = bd[kk-1]; bd[kk-1] = td;
                    int   ti = bi[kk]; bi[kk] = bi[kk-1]; bi[kk-1] = ti;
                }
            }
        }
    }
}

__global__ __launch_bounds__(TPB, 4) void gcn_main(
        const float* __restrict__ xin,   // (B, C, H, W)
        const float* __restrict__ pos,   // (1, C, H, W)
        const float* __restrict__ rel,   // (1, N, N)
        const float* __restrict__ W1,  const float* __restrict__ B1,   // g_fc1 32x32
        const float* __restrict__ WC,  const float* __restrict__ BC,   // g_conv 64x64
        const float* __restrict__ W2,  const float* __restrict__ B2,   // g_fc2 32x64
        const float* __restrict__ F1,  const float* __restrict__ FB1,  // f_fc1 32x32
        const float* __restrict__ F2,  const float* __restrict__ FB2,  // f_fc2 32x32
        float* __restrict__ out) {
    const int t = threadIdx.x;
    const int n = t >> 2;           // node 0..143
    const int s = t & 3;            // quad sub-lane
    const long bb = blockIdx.x;

    __shared__ __align__(16) float  s_xfT[NN * PAD];  // (n,c) g_fc1 output
    __shared__ float2 s_sr[NN];                       // (sq, rinv)

    const float* xb = xin + bb * (CH * NN) + n;
    const float* pb = pos + n;

    // ---- phase 1+2: tmp chunk (8 ch) per lane; xf = W1@tmp via quad K-split ----
    float tc[8];
    #pragma unroll
    for (int cc = 0; cc < 8; ++cc) {
        int c = 8 * s + cc;
        tc[cc] = xb[c * NN] + pb[c * NN];
    }
    float xfn[CH];
    #pragma unroll
    for (int o = 0; o < CH; ++o) {
        const float4* w = (const float4*)&W1[o * CH + 8 * s];
        float4 w0 = w[0], w1v = w[1];
        xfn[o] = w0.x*tc[0] + w0.y*tc[1] + w0.z*tc[2] + w0.w*tc[3]
               + w1v.x*tc[4] + w1v.y*tc[5] + w1v.z*tc[6] + w1v.w*tc[7];
    }
    #pragma unroll
    for (int o = 0; o < CH; ++o) xfn[o] += __shfl_xor(xfn[o], 1);
    #pragma unroll
    for (int o = 0; o < CH; ++o) xfn[o] += __shfl_xor(xfn[o], 2);
    #pragma unroll
    for (int o = 0; o < CH; ++o) xfn[o] += B1[o];

    float sum = 0.f;
    #pragma unroll
    for (int o = 0; o < CH; ++o) sum = fmaf(xfn[o], xfn[o], sum);
    const float rn  = 1.0f / fmaxf(sqrtf(sum), 1e-12f);
    const float sqn = sum * rn * rn;
    if (s == 0) s_sr[n] = make_float2(sqn, rn);

    // write own chunk of the row to LDS (values picked by selects, no dyn index)
    float own[8];
    #pragma unroll
    for (int oo = 0; oo < 8; ++oo) own[oo] = PICK8(xfn, s, oo);
    {
        float4* dst = (float4*)&s_xfT[n * PAD + 8 * s];
        dst[0] = make_float4(own[0], own[1], own[2], own[3]);
        dst[1] = make_float4(own[4], own[5], own[6], own[7]);
    }
    __syncthreads();   // the only barrier

    // ---- phase 4: k-NN, quad-split m-range (36 each), local top-9 + merge ----
    float bestd[KNN];
    int   besti[KNN];
    #pragma unroll
    for (int k = 0; k < KNN; ++k) { bestd[k] = INFINITY; besti[k] = 0; }
    const float rn2 = 2.0f * rn;
    const float* reln = rel + n * NN + 36 * s;

    for (int blk = 0; blk < 3; ++blk) {
        float rl[12];
        const float4* rp = (const float4*)(reln + 12 * blk);
        #pragma unroll
        for (int q = 0; q < 3; ++q) {
            float4 v = rp[q];
            rl[4*q] = v.x; rl[4*q+1] = v.y; rl[4*q+2] = v.z; rl[4*q+3] = v.w;
        }
        #pragma unroll
        for (int mm = 0; mm < 12; ++mm) {
            const int m = 36 * s + 12 * blk + mm;
            const float4* row = (const float4*)&s_xfT[m * PAD];
            float dot = 0.f;
            #pragma unroll
            for (int q = 0; q < 8; ++q) {
                float4 v = row[q];
                dot += xfn[4*q] * v.x + xfn[4*q+1] * v.y
                     + xfn[4*q+2] * v.z + xfn[4*q+3] * v.w;
            }
            float2 sr = s_sr[m];
            float d = (sqn + sr.x + rl[mm]) - rn2 * sr.y * dot;
            if (d < bestd[KNN - 1]) {   // strict <: lower m inserted first
                bestd[KNN - 1] = d; besti[KNN - 1] = m;
                #pragma unroll
                for (int k = KNN - 1; k > 0; --k) {
                    if (bestd[k] < bestd[k - 1]) {
                        float td = bestd[k]; bestd[k] = bestd[k - 1]; bestd[k - 1] = td;
                        int   ti = besti[k]; besti[k] = besti[k - 1]; besti[k - 1] = ti;
                    }
                }
            }
        }
    }
    quad_merge(bestd, besti, 1);
    quad_merge(bestd, besti, 2);   // all 4 lanes now hold identical global top-9

    // ---- phase 5: max-relative, quad-split channels; allgather to full 32 ----
    float mr[8];
    #pragma unroll
    for (int k = 0; k < 8; ++k) mr[k] = -INFINITY;
    #pragma unroll
    for (int k = 0; k < KNN; ++k) {
        const float4* g4 = (const float4*)&s_xfT[besti[k] * PAD + 8 * s];
        float4 a = g4[0], b4 = g4[1];
        mr[0] = fmaxf(mr[0], a.x);  mr[1] = fmaxf(mr[1], a.y);
        mr[2] = fmaxf(mr[2], a.z);  mr[3] = fmaxf(mr[3], a.w);
        mr[4] = fmaxf(mr[4], b4.x); mr[5] = fmaxf(mr[5], b4.y);
        mr[6] = fmaxf(mr[6], b4.z); mr[7] = fmaxf(mr[7], b4.w);
    }
    #pragma unroll
    for (int cc = 0; cc < 8; ++cc) mr[cc] -= own[cc];
    float mrelF[CH];
    quad_allgather(mr, mrelF, s);

    // ---- phase 6: conv j-split (16/lane): h = gelu(WC@stacked+BC) ----
    float h[16];
    #pragma unroll 4
    for (int jj = 0; jj < 16; ++jj) {
        const int j = 16 * s + jj;
        const float4* wr = (const float4*)&WC[j * 2 * CH];
        float acc = BC[j];
        #pragma unroll
        for (int q = 0; q < 16; ++q) {
            float4 w = wr[q];
            const int c = 2 * q;
            acc += w.x * xfn[c] + w.y * mrelF[c] + w.z * xfn[c+1] + w.w * mrelF[c+1];
        }
        h[jj] = gelu_exact(acc);
    }
    // x2r partial = residual chunk (predicated) + W2 partial; quad-reduce
    float x2r[CH];
    #pragma unroll
    for (int o = 0; o < CH; ++o) x2r[o] = ((o >> 3) == s) ? tc[o & 7] : 0.0f;
    #pragma unroll
    for (int o = 0; o < CH; ++o) {
        const float4* w4 = (const float4*)&W2[o * 2 * CH + 16 * s];
        float acc = x2r[o];
        #pragma unroll
        for (int q = 0; q < 4; ++q) {
            float4 w = w4[q];
            acc += w.x * h[4*q] + w.y * h[4*q+1] + w.z * h[4*q+2] + w.w * h[4*q+3];
        }
        x2r[o] = acc;
    }
    #pragma unroll
    for (int o = 0; o < CH; ++o) x2r[o] += __shfl_xor(x2r[o], 1);
    #pragma unroll
    for (int o = 0; o < CH; ++o) x2r[o] += __shfl_xor(x2r[o], 2);
    #pragma unroll
    for (int o = 0; o < CH; ++o) x2r[o] += B2[o];

    // ---- phase 7: FFN o-split (8/lane), allgather hidden, store ----
    float yv8[8];
    #pragma unroll
    for (int oo = 0; oo < 8; ++oo) {
        const int o = 8 * s + oo;
        const float4* f4 = (const float4*)&F1[o * CH];
        float acc = FB1[o];
        #pragma unroll
        for (int q = 0; q < 8; ++q) {
            float4 w = f4[q];
            acc += w.x * x2r[4*q] + w.y * x2r[4*q+1] + w.z * x2r[4*q+2] + w.w * x2r[4*q+3];
        }
        yv8[oo] = gelu_exact(acc);
    }
    float yvF[CH];
    quad_allgather(yv8, yvF, s);

    float* ob = out + bb * (CH * NN) + n;
    #pragma unroll
    for (int oo = 0; oo < 8; ++oo) {
        const int o = 8 * s + oo;
        const float4* f4 = (const float4*)&F2[o * CH];
        float acc = FB2[o];
        #pragma unroll
        for (int q = 0; q < 8; ++q) {
            float4 w = f4[q];
            acc += w.x * yvF[4*q] + w.y * yvF[4*q+1] + w.z * yvF[4*q+2] + w.w * yvF[4*q+3];
        }
        ob[o * NN] = acc + PICK8(x2r, s, oo);
    }
}

extern "C" void kernel_launch(void* const* d_in, const int* in_sizes, int n_in,
                              void* d_out, int out_size, void* d_ws, size_t ws_size,
                              hipStream_t stream) {
    const float* xin = (const float*)d_in[0];
    const float* pos = (const float*)d_in[1];
    const float* rel = (const float*)d_in[2];
    const float* w1  = (const float*)d_in[3];
    const float* b1  = (const float*)d_in[4];
    const float* wc  = (const float*)d_in[5];
    const float* bc  = (const float*)d_in[6];
    const float* w2  = (const float*)d_in[7];
    const float* b2  = (const float*)d_in[8];
    const float* f1  = (const float*)d_in[9];
    const float* fb1 = (const float*)d_in[10];
    const float* f2  = (const float*)d_in[11];
    const float* fb2 = (const float*)d_in[12];
    float* out = (float*)d_out;

    dim3 grid(BATCH), blk(TPB);
    gcn_main<<<grid, blk, 0, stream>>>(xin, pos, rel,
                                       w1, b1, wc, bc, w2, b2,
                                       f1, fb1, f2, fb2, out);
}

// Round 6
// 1482.219 us; speedup vs baseline: 1.2625x; 1.2625x over previous
//
#include <hip/hip_runtime.h>
#include <math.h>

// Problem constants (fixed by reference)
#define BATCH 2048
#define CH    32      // C
#define NN    144     // H*W = 12*12
#define KNN   9
#define PAD   36      // LDS row stride (floats): rows 2-way bank aliased = free
#define TPB   576     // 4 threads per node, one batch per block, 9 waves

// exact GELU: x * 0.5 * (1 + erf(x/sqrt(2)))  (jax.nn.gelu approximate=False)
__device__ __forceinline__ float gelu_exact(float x) {
    return 0.5f * x * (1.0f + erff(x * 0.70710678118654752440f));
}

// pick arr[8*s + oo] without dynamic register indexing (oo compile-time)
#define PICK8(arr, s, oo) ((s)==0 ? (arr)[oo] : (s)==1 ? (arr)[8+(oo)] : \
                           (s)==2 ? (arr)[16+(oo)] : (arr)[24+(oo)])

// ordered allgather of 8-chunks across a quad: out[32] = concat(chunk0..3)
__device__ __forceinline__ void quad_allgather(const float a[8], float out[32], int s) {
    float b[8];
    #pragma unroll
    for (int k = 0; k < 8; ++k) b[k] = __shfl_xor(a[k], 1);
    float p[16];
    const bool o1 = (s & 1);
    #pragma unroll
    for (int k = 0; k < 8; ++k) { p[k] = o1 ? b[k] : a[k]; p[8 + k] = o1 ? a[k] : b[k]; }
    float q[16];
    #pragma unroll
    for (int k = 0; k < 16; ++k) q[k] = __shfl_xor(p[k], 2);
    const bool o2 = (s & 2);
    #pragma unroll
    for (int k = 0; k < 16; ++k) { out[k] = o2 ? q[k] : p[k]; out[16 + k] = o2 ? p[k] : q[k]; }
}

// merge partner's sorted top-9 into mine; lex (d, idx) preserves lax.top_k tie-break
__device__ __forceinline__ void quad_merge(float bd[KNN], int bi[KNN], int mask) {
    float od[KNN]; int oi[KNN];
    #pragma unroll
    for (int k = 0; k < KNN; ++k) { od[k] = __shfl_xor(bd[k], mask); oi[k] = __shfl_xor(bi[k], mask); }
    #pragma unroll
    for (int k = 0; k < KNN; ++k) {
        float d = od[k]; int ix = oi[k];
        if (d < bd[KNN-1] || (d == bd[KNN-1] && ix < bi[KNN-1])) {
            bd[KNN-1] = d; bi[KNN-1] = ix;
            #pragma unroll
            for (int kk = KNN-1; kk > 0; --kk) {
                bool sw = bd[kk] < bd[kk-1] || (bd[kk] == bd[kk-1] && bi[kk] < bi[kk-1]);
                if (sw) {
                    float td = bd[kk]; bd[kk] = bd[kk-1]; bd[kk-1] = td;
                    int   ti = bi[kk]; bi[kk] = bi[kk-1]; bi[kk-1] = ti;
                }
            }
        }
    }
}

// NOTE: second launch_bounds arg is min WAVES PER EU. (TPB,4) capped VGPRs at 64
// and spilled ~100 regs/thread to scratch (R5: 2.9GB/dispatch HBM traffic).
__global__ __launch_bounds__(TPB, 2) void gcn_main(
        const float* __restrict__ xin,   // (B, C, H, W)
        const float* __restrict__ pos,   // (1, C, H, W)
        const float* __restrict__ rel,   // (1, N, N)
        const float* __restrict__ W1,  const float* __restrict__ B1,   // g_fc1 32x32
        const float* __restrict__ WC,  const float* __restrict__ BC,   // g_conv 64x64
        const float* __restrict__ W2,  const float* __restrict__ B2,   // g_fc2 32x64
        const float* __restrict__ F1,  const float* __restrict__ FB1,  // f_fc1 32x32
        const float* __restrict__ F2,  const float* __restrict__ FB2,  // f_fc2 32x32
        float* __restrict__ out) {
    const int t = threadIdx.x;
    const int n = t >> 2;           // node 0..143
    const int s = t & 3;            // quad sub-lane
    const long bb = blockIdx.x;

    __shared__ __align__(16) float  s_xfT[NN * PAD];  // (n,c) g_fc1 output
    __shared__ float2 s_sr[NN];                       // (sq, rinv)

    const float* xb = xin + bb * (CH * NN) + n;
    const float* pb = pos + n;

    // ---- phase 1+2: tmp chunk (8 ch) per lane; xf = W1@tmp via quad K-split ----
    float tc[8];
    #pragma unroll
    for (int cc = 0; cc < 8; ++cc) {
        int c = 8 * s + cc;
        tc[cc] = xb[c * NN] + pb[c * NN];
    }
    float xfn[CH];
    #pragma unroll
    for (int o = 0; o < CH; ++o) {
        const float4* w = (const float4*)&W1[o * CH + 8 * s];
        float4 w0 = w[0], w1v = w[1];
        xfn[o] = w0.x*tc[0] + w0.y*tc[1] + w0.z*tc[2] + w0.w*tc[3]
               + w1v.x*tc[4] + w1v.y*tc[5] + w1v.z*tc[6] + w1v.w*tc[7];
    }
    #pragma unroll
    for (int o = 0; o < CH; ++o) xfn[o] += __shfl_xor(xfn[o], 1);
    #pragma unroll
    for (int o = 0; o < CH; ++o) xfn[o] += __shfl_xor(xfn[o], 2);
    #pragma unroll
    for (int o = 0; o < CH; ++o) xfn[o] += B1[o];

    float sum = 0.f;
    #pragma unroll
    for (int o = 0; o < CH; ++o) sum = fmaf(xfn[o], xfn[o], sum);
    const float rn  = 1.0f / fmaxf(sqrtf(sum), 1e-12f);
    const float sqn = sum * rn * rn;
    if (s == 0) s_sr[n] = make_float2(sqn, rn);

    // write own chunk of the row to LDS (values picked by selects, no dyn index)
    float own[8];
    #pragma unroll
    for (int oo = 0; oo < 8; ++oo) own[oo] = PICK8(xfn, s, oo);
    {
        float4* dst = (float4*)&s_xfT[n * PAD + 8 * s];
        dst[0] = make_float4(own[0], own[1], own[2], own[3]);
        dst[1] = make_float4(own[4], own[5], own[6], own[7]);
    }
    __syncthreads();   // the only barrier

    // ---- phase 4: k-NN, quad-split m-range (36 each), local top-9 + merge ----
    float bestd[KNN];
    int   besti[KNN];
    #pragma unroll
    for (int k = 0; k < KNN; ++k) { bestd[k] = INFINITY; besti[k] = 0; }
    const float rn2 = 2.0f * rn;
    const float* reln = rel + n * NN + 36 * s;

    for (int blk = 0; blk < 3; ++blk) {
        float rl[12];
        const float4* rp = (const float4*)(reln + 12 * blk);
        #pragma unroll
        for (int q = 0; q < 3; ++q) {
            float4 v = rp[q];
            rl[4*q] = v.x; rl[4*q+1] = v.y; rl[4*q+2] = v.z; rl[4*q+3] = v.w;
        }
        #pragma unroll
        for (int mm = 0; mm < 12; ++mm) {
            const int m = 36 * s + 12 * blk + mm;
            const float4* row = (const float4*)&s_xfT[m * PAD];
            float dot = 0.f;
            #pragma unroll
            for (int q = 0; q < 8; ++q) {
                float4 v = row[q];
                dot += xfn[4*q] * v.x + xfn[4*q+1] * v.y
                     + xfn[4*q+2] * v.z + xfn[4*q+3] * v.w;
            }
            float2 sr = s_sr[m];
            float d = (sqn + sr.x + rl[mm]) - rn2 * sr.y * dot;
            if (d < bestd[KNN - 1]) {   // strict <: lower m inserted first
                bestd[KNN - 1] = d; besti[KNN - 1] = m;
                #pragma unroll
                for (int k = KNN - 1; k > 0; --k) {
                    if (bestd[k] < bestd[k - 1]) {
                        float td = bestd[k]; bestd[k] = bestd[k - 1]; bestd[k - 1] = td;
                        int   ti = besti[k]; besti[k] = besti[k - 1]; besti[k - 1] = ti;
                    }
                }
            }
        }
    }
    quad_merge(bestd, besti, 1);
    quad_merge(bestd, besti, 2);   // all 4 lanes now hold identical global top-9

    // ---- phase 5: max-relative, quad-split channels; allgather to full 32 ----
    float mr[8];
    #pragma unroll
    for (int k = 0; k < 8; ++k) mr[k] = -INFINITY;
    #pragma unroll
    for (int k = 0; k < KNN; ++k) {
        const float4* g4 = (const float4*)&s_xfT[besti[k] * PAD + 8 * s];
        float4 a = g4[0], b4 = g4[1];
        mr[0] = fmaxf(mr[0], a.x);  mr[1] = fmaxf(mr[1], a.y);
        mr[2] = fmaxf(mr[2], a.z);  mr[3] = fmaxf(mr[3], a.w);
        mr[4] = fmaxf(mr[4], b4.x); mr[5] = fmaxf(mr[5], b4.y);
        mr[6] = fmaxf(mr[6], b4.z); mr[7] = fmaxf(mr[7], b4.w);
    }
    #pragma unroll
    for (int cc = 0; cc < 8; ++cc) mr[cc] -= own[cc];
    float mrelF[CH];
    quad_allgather(mr, mrelF, s);

    // ---- phase 6: conv j-split (16/lane): h = gelu(WC@stacked+BC) ----
    float h[16];
    #pragma unroll 4
    for (int jj = 0; jj < 16; ++jj) {
        const int j = 16 * s + jj;
        const float4* wr = (const float4*)&WC[j * 2 * CH];
        float acc = BC[j];
        #pragma unroll
        for (int q = 0; q < 16; ++q) {
            float4 w = wr[q];
            const int c = 2 * q;
            acc += w.x * xfn[c] + w.y * mrelF[c] + w.z * xfn[c+1] + w.w * mrelF[c+1];
        }
        h[jj] = gelu_exact(acc);
    }
    // x2r partial = residual chunk (predicated) + W2 partial; quad-reduce
    float x2r[CH];
    #pragma unroll
    for (int o = 0; o < CH; ++o) x2r[o] = ((o >> 3) == s) ? tc[o & 7] : 0.0f;
    #pragma unroll
    for (int o = 0; o < CH; ++o) {
        const float4* w4 = (const float4*)&W2[o * 2 * CH + 16 * s];
        float acc = x2r[o];
        #pragma unroll
        for (int q = 0; q < 4; ++q) {
            float4 w = w4[q];
            acc += w.x * h[4*q] + w.y * h[4*q+1] + w.z * h[4*q+2] + w.w * h[4*q+3];
        }
        x2r[o] = acc;
    }
    #pragma unroll
    for (int o = 0; o < CH; ++o) x2r[o] += __shfl_xor(x2r[o], 1);
    #pragma unroll
    for (int o = 0; o < CH; ++o) x2r[o] += __shfl_xor(x2r[o], 2);
    #pragma unroll
    for (int o = 0; o < CH; ++o) x2r[o] += B2[o];

    // ---- phase 7: FFN o-split (8/lane), allgather hidden, store ----
    float yv8[8];
    #pragma unroll
    for (int oo = 0; oo < 8; ++oo) {
        const int o = 8 * s + oo;
        const float4* f4 = (const float4*)&F1[o * CH];
        float acc = FB1[o];
        #pragma unroll
        for (int q = 0; q < 8; ++q) {
            float4 w = f4[q];
            acc += w.x * x2r[4*q] + w.y * x2r[4*q+1] + w.z * x2r[4*q+2] + w.w * x2r[4*q+3];
        }
        yv8[oo] = gelu_exact(acc);
    }
    float yvF[CH];
    quad_allgather(yv8, yvF, s);

    float* ob = out + bb * (CH * NN) + n;
    #pragma unroll
    for (int oo = 0; oo < 8; ++oo) {
        const int o = 8 * s + oo;
        const float4* f4 = (const float4*)&F2[o * CH];
        float acc = FB2[o];
        #pragma unroll
        for (int q = 0; q < 8; ++q) {
            float4 w = f4[q];
            acc += w.x * yvF[4*q] + w.y * yvF[4*q+1] + w.z * yvF[4*q+2] + w.w * yvF[4*q+3];
        }
        ob[o * NN] = acc + PICK8(x2r, s, oo);
    }
}

extern "C" void kernel_launch(void* const* d_in, const int* in_sizes, int n_in,
                              void* d_out, int out_size, void* d_ws, size_t ws_size,
                              hipStream_t stream) {
    const float* xin = (const float*)d_in[0];
    const float* pos = (const float*)d_in[1];
    const float* rel = (const float*)d_in[2];
    const float* w1  = (const float*)d_in[3];
    const float* b1  = (const float*)d_in[4];
    const float* wc  = (const float*)d_in[5];
    const float* bc  = (const float*)d_in[6];
    const float* w2  = (const float*)d_in[7];
    const float* b2  = (const float*)d_in[8];
    const float* f1  = (const float*)d_in[9];
    const float* fb1 = (const float*)d_in[10];
    const float* f2  = (const float*)d_in[11];
    const float* fb2 = (const float*)d_in[12];
    float* out = (float*)d_out;

    dim3 grid(BATCH), blk(TPB);
    gcn_main<<<grid, blk, 0, stream>>>(xin, pos, rel,
                                       w1, b1, wc, bc, w2, b2,
                                       f1, fb1, f2, fb2, out);
}

// Round 7
// 549.441 us; speedup vs baseline: 3.4058x; 2.6977x over previous
//
#include <hip/hip_runtime.h>
#include <math.h>

// Problem constants (fixed by reference)
#define BATCH 2048
#define CH    32      // C
#define NN    144     // H*W = 12*12
#define KNN   9
#define PAD   36      // LDS row stride (floats): 16B-aligned, 2-way bank alias = free
#define TPB   192     // 3 waves; threads 0..143 active, one node each

// exact GELU: x * 0.5 * (1 + erf(x/sqrt(2)))  (jax.nn.gelu approximate=False)
__device__ __forceinline__ float gelu_exact(float x) {
    return 0.5f * x * (1.0f + erff(x * 0.70710678118654752440f));
}

// One batch element per workgroup; one thread per node.
// LDS ~21.9KB -> ~7 blocks/CU resident (R3 was 47.6KB -> ~2). No spills at ~80 VGPR.
__global__ __launch_bounds__(TPB) void gcn_main(
        const float* __restrict__ xin,   // (B, C, H, W)
        const float* __restrict__ pos,   // (1, C, H, W)
        const float* __restrict__ rel,   // (1, N, N)
        const float* __restrict__ W1,  const float* __restrict__ B1,   // g_fc1 32x32
        const float* __restrict__ WC,  const float* __restrict__ BC,   // g_conv 64x64
        const float* __restrict__ W2,  const float* __restrict__ B2,   // g_fc2 32x64
        const float* __restrict__ F1,  const float* __restrict__ FB1,  // f_fc1 32x32
        const float* __restrict__ F2,  const float* __restrict__ FB2,  // f_fc2 32x32
        float* __restrict__ out) {
    const int t = threadIdx.x;
    const int n = t;                 // node index (threads >= NN idle)
    const long bb = blockIdx.x;

    __shared__ __align__(16) float  s_xfT[NN * PAD];  // (n,c) g_fc1 output
    __shared__ float2 s_sr[NN];                       // (sq, rinv)

    const float* xb = xin + bb * (CH * NN) + n;   // column n (coalesced across lanes)
    const float* pb = pos + n;

    float xfn[CH];   // this node's xf row, lives in regs through the tail

    // ---- phase 1+2 fused: tmp col from global; xf = W1@tmp + B1 (W1 via s_load) ----
    if (t < NN) {
        float tc[CH];
        #pragma unroll
        for (int c = 0; c < CH; ++c) tc[c] = xb[c * NN] + pb[c * NN];
        float sum = 0.f;
        #pragma unroll
        for (int o = 0; o < CH; ++o) {
            float acc = B1[o];
            #pragma unroll
            for (int c = 0; c < CH; ++c) acc += W1[o * CH + c] * tc[c];
            xfn[o] = acc;
            sum += acc * acc;
        }
        float4* xr = (float4*)&s_xfT[n * PAD];
        #pragma unroll
        for (int q = 0; q < 8; ++q)
            xr[q] = make_float4(xfn[4*q], xfn[4*q+1], xfn[4*q+2], xfn[4*q+3]);
        float r = 1.0f / fmaxf(sqrtf(sum), 1e-12f);
        s_sr[n] = make_float2(sum * r * r, r);
    }
    __syncthreads();
    if (t >= NN) return;   // tail is per-thread, read-only LDS: no more barriers

    // ---- phase 4: k-NN over all m ----
    const float sqn = s_sr[n].x;
    const float rn2 = 2.0f * s_sr[n].y;
    float bestd[KNN];
    int   besti[KNN];
    #pragma unroll
    for (int k = 0; k < KNN; ++k) { bestd[k] = INFINITY; besti[k] = 0; }

    const float* reln = rel + n * NN;
    for (int mb = 0; mb < NN / 16; ++mb) {
        float rl[16];
        const float4* rp = (const float4*)(reln + mb * 16);
        #pragma unroll
        for (int q = 0; q < 4; ++q) {
            float4 v = rp[q];
            rl[4*q] = v.x; rl[4*q+1] = v.y; rl[4*q+2] = v.z; rl[4*q+3] = v.w;
        }
        #pragma unroll
        for (int mm = 0; mm < 16; ++mm) {
            const int m = mb * 16 + mm;
            const float4* row = (const float4*)&s_xfT[m * PAD];  // broadcast read
            float dot = 0.f;
            #pragma unroll
            for (int q = 0; q < 8; ++q) {
                float4 v = row[q];
                dot += xfn[4*q] * v.x + xfn[4*q+1] * v.y
                     + xfn[4*q+2] * v.z + xfn[4*q+3] * v.w;
            }
            float2 sr = s_sr[m];
            float d = (sqn + sr.x + rl[mm]) - rn2 * sr.y * dot;
            // strict < matches lax.top_k tie-break (lower index wins; m ascends)
            if (d < bestd[KNN - 1]) {
                bestd[KNN - 1] = d; besti[KNN - 1] = m;
                #pragma unroll
                for (int k = KNN - 1; k > 0; --k) {
                    if (bestd[k] < bestd[k - 1]) {
                        float td = bestd[k]; bestd[k] = bestd[k - 1]; bestd[k - 1] = td;
                        int   ti = besti[k]; besti[k] = besti[k - 1]; besti[k - 1] = ti;
                    }
                }
            }
        }
    }

    // ---- residual base: x2r = B2 + tmp (global re-read, L1-hot, coalesced) ----
    float x2r[CH];
    #pragma unroll
    for (int o = 0; o < CH; ++o) x2r[o] = B2[o] + xb[o * NN] + pb[o * NN];

    // ---- phase 5: max-relative (gathered rows) ----
    float mrel[CH];
    #pragma unroll
    for (int c = 0; c < CH; ++c) mrel[c] = -INFINITY;
    #pragma unroll
    for (int k = 0; k < KNN; ++k) {
        const float4* nr = (const float4*)&s_xfT[besti[k] * PAD];
        #pragma unroll
        for (int q = 0; q < 8; ++q) {
            float4 v = nr[q];
            mrel[4*q]   = fmaxf(mrel[4*q],   v.x);
            mrel[4*q+1] = fmaxf(mrel[4*q+1], v.y);
            mrel[4*q+2] = fmaxf(mrel[4*q+2], v.z);
            mrel[4*q+3] = fmaxf(mrel[4*q+3], v.w);
        }
    }
    #pragma unroll
    for (int c = 0; c < CH; ++c) mrel[c] -= xfn[c];

    // ---- phase 6: hc = gelu(WC@stacked + BC); x2r += W2@hc (streamed per j) ----
    // stacked[2c] = xfn[c], stacked[2c+1] = mrel[c]; WC/W2 rows wave-uniform -> s_load
    #pragma unroll 2
    for (int j = 0; j < 2 * CH; ++j) {
        float acc = BC[j];
        const float* wr = WC + j * 2 * CH;
        #pragma unroll
        for (int c = 0; c < CH; ++c)
            acc += wr[2*c] * xfn[c] + wr[2*c + 1] * mrel[c];
        float h = gelu_exact(acc);
        #pragma unroll
        for (int o = 0; o < CH; ++o) x2r[o] += W2[o * 2 * CH + j] * h;
    }

    // ---- phase 7: FFN + residual + store ----
    float yv[CH];
    #pragma unroll
    for (int o = 0; o < CH; ++o) {
        float acc = FB1[o];
        #pragma unroll
        for (int c = 0; c < CH; ++c) acc += F1[o * CH + c] * x2r[c];
        yv[o] = gelu_exact(acc);
    }
    float* ob = out + bb * (CH * NN) + n;
    #pragma unroll
    for (int o = 0; o < CH; ++o) {
        float acc = FB2[o];
        #pragma unroll
        for (int c = 0; c < CH; ++c) acc += F2[o * CH + c] * yv[c];
        ob[o * NN] = acc + x2r[o];
    }
}

extern "C" void kernel_launch(void* const* d_in, const int* in_sizes, int n_in,
                              void* d_out, int out_size, void* d_ws, size_t ws_size,
                              hipStream_t stream) {
    const float* xin = (const float*)d_in[0];
    const float* pos = (const float*)d_in[1];
    const float* rel = (const float*)d_in[2];
    const float* w1  = (const float*)d_in[3];
    const float* b1  = (const float*)d_in[4];
    const float* wc  = (const float*)d_in[5];
    const float* bc  = (const float*)d_in[6];
    const float* w2  = (const float*)d_in[7];
    const float* b2  = (const float*)d_in[8];
    const float* f1  = (const float*)d_in[9];
    const float* fb1 = (const float*)d_in[10];
    const float* f2  = (const float*)d_in[11];
    const float* fb2 = (const float*)d_in[12];
    float* out = (float*)d_out;

    dim3 grid(BATCH), blk(TPB);
    gcn_main<<<grid, blk, 0, stream>>>(xin, pos, rel,
                                       w1, b1, wc, bc, w2, b2,
                                       f1, fb1, f2, fb2, out);
}